// Round 3
// baseline (322.342 us; speedup 1.0000x reference)
//
#include <hip/hip_runtime.h>

// Problem constants: B=32, N=4096, C=1152, K = int(N*0.1) = 409
#define B_ 32
#define N_ 4096
#define C_ 1152
#define K_ 409

#define NBLK 2048
#define PATCH_PER_BLK 64          // (B_*N_)/NBLK
#define ITERS 16                  // patches per wave (4 waves/block)
#define BLOCKS_PER_ROW 64         // N_ / PATCH_PER_BLK

typedef float f32x4 __attribute__((ext_vector_type(4)));

// Fused: scores + |.| to workspace; the last block to finish a batch row
// (device-scope counter) radix-selects the K-th largest and writes the mean.
__global__ __launch_bounds__(256) void fused_kernel(
    const float* __restrict__ feat, const float* __restrict__ W,
    const float* __restrict__ bias, float* __restrict__ absS,
    unsigned* __restrict__ cnt, float* __restrict__ out) {
  __shared__ union {
    f32x4 Ws[C_ / 4];                       // 4.5 KB, used only in phase 1
    struct {                                // used only by the last block
      float vals[N_];                       // 16 KB
      unsigned hist[256];
      unsigned wsum[4];
      unsigned sel[2];
      float sredf[4];
      unsigned cred[4];
      int islast;                           // offset > Ws size: no overlap hazard
    } tk;
  } sh;

  const int t = threadIdx.x;
  const int wave = t >> 6;
  const int lane = t & 63;

  for (int i = t; i < C_ / 4; i += 256)
    sh.Ws[i] = reinterpret_cast<const f32x4*>(W)[i];
  __syncthreads();

  const float b0 = bias[0];
  const f32x4 w0 = sh.Ws[lane];
  const f32x4 w1 = sh.Ws[lane + 64];
  const f32x4 w2 = sh.Ws[lane + 128];
  const f32x4 w3 = sh.Ws[lane + 192];
  const f32x4 w4 = (lane < 32) ? sh.Ws[256 + lane] : (f32x4)0.f;

  // ---- Phase 1: streaming dot products, reductions deferred for MLP ----
  const int patch0 = blockIdx.x * PATCH_PER_BLK + wave;
  const f32x4* fbase = reinterpret_cast<const f32x4*>(feat);
  float pacc[ITERS];
#pragma unroll
  for (int it = 0; it < ITERS; ++it) {
    const f32x4* f4 = fbase + (size_t)(patch0 + it * 4) * (C_ / 4);
    f32x4 vacc = __builtin_nontemporal_load(&f4[lane]) * w0;
    vacc += __builtin_nontemporal_load(&f4[lane + 64]) * w1;
    vacc += __builtin_nontemporal_load(&f4[lane + 128]) * w2;
    vacc += __builtin_nontemporal_load(&f4[lane + 192]) * w3;
    if (lane < 32) vacc += __builtin_nontemporal_load(&f4[256 + lane]) * w4;
    pacc[it] = vacc[0] + vacc[1] + vacc[2] + vacc[3];
  }
#pragma unroll
  for (int it = 0; it < ITERS; ++it) {
    float a = pacc[it];
#pragma unroll
    for (int off = 32; off > 0; off >>= 1) a += __shfl_down(a, off, 64);
    if (lane == 0)
      __hip_atomic_store(&absS[patch0 + it * 4], fabsf(a + b0),
                         __ATOMIC_RELAXED, __HIP_MEMORY_SCOPE_AGENT);
  }

  // ---- Last-block election (release: stores -> fence -> barrier -> atomic) ----
  const int row = blockIdx.x / BLOCKS_PER_ROW;
  __threadfence();
  __syncthreads();
  if (t == 0) {
    unsigned old = atomicAdd(&cnt[row], 1u);
    sh.tk.islast = (old == BLOCKS_PER_ROW - 1);
  }
  __syncthreads();
  if (!sh.tk.islast) return;
  __threadfence();  // acquire

  // ---- Phase 2 (one block per row): stage row, radix-select K-th largest ----
  const float* rowp = absS + (size_t)row * N_;
  for (int i = t; i < N_; i += 256)
    sh.tk.vals[i] = __hip_atomic_load(&rowp[i], __ATOMIC_RELAXED,
                                      __HIP_MEMORY_SCOPE_AGENT);
  __syncthreads();

  unsigned prefix = 0, k = K_;
#pragma unroll
  for (int p = 0; p < 4; ++p) {
    const int shift = 24 - 8 * p;
    const unsigned hmask = (p == 0) ? 0u : (0xFFFFFFFFu << (shift + 8));
    sh.tk.hist[t] = 0;
    __syncthreads();
    for (int i = t; i < N_; i += 256) {
      const unsigned e = __float_as_uint(sh.tk.vals[i]);
      if ((e & hmask) == (prefix & hmask))
        atomicAdd(&sh.tk.hist[(e >> shift) & 255u], 1u);
    }
    __syncthreads();
    const unsigned own = sh.tk.hist[t];
    unsigned x = own;  // inclusive suffix scan within wave via shfl
#pragma unroll
    for (int off = 1; off < 64; off <<= 1) {
      const unsigned v = __shfl_down(x, off, 64);
      if (lane + off < 64) x += v;
    }
    if (lane == 0) sh.tk.wsum[wave] = x;
    __syncthreads();
    unsigned cum_ge = x;
    for (int w = wave + 1; w < 4; ++w) cum_ge += sh.tk.wsum[w];
    const unsigned cnt_gt = cum_ge - own;
    if (cum_ge >= k && cnt_gt < k) {  // exactly one thread
      sh.tk.sel[0] = (unsigned)t;
      sh.tk.sel[1] = k - cnt_gt;
    }
    __syncthreads();
    prefix |= sh.tk.sel[0] << shift;
    k = sh.tk.sel[1];
    __syncthreads();
  }
  const float thr = __uint_as_float(prefix);

  // Sum strictly-greater elements; ties filled at thr.
  float sum = 0.f;
  unsigned cgt = 0;
  for (int i = t; i < N_; i += 256) {
    const float v = sh.tk.vals[i];
    if (v > thr) { sum += v; cgt++; }
  }
#pragma unroll
  for (int off = 32; off > 0; off >>= 1) {
    sum += __shfl_down(sum, off, 64);
    cgt += __shfl_down(cgt, off, 64);
  }
  if (lane == 0) { sh.tk.cred[wave] = cgt; sh.tk.sredf[wave] = sum; }
  __syncthreads();
  if (t == 0) {
    const unsigned cg = sh.tk.cred[0] + sh.tk.cred[1] + sh.tk.cred[2] + sh.tk.cred[3];
    const float sg = sh.tk.sredf[0] + sh.tk.sredf[1] + sh.tk.sredf[2] + sh.tk.sredf[3];
    out[row] = (sg + (float)(K_ - (int)cg) * thr) / (float)K_;
  }
}

extern "C" void kernel_launch(void* const* d_in, const int* in_sizes, int n_in,
                              void* d_out, int out_size, void* d_ws, size_t ws_size,
                              hipStream_t stream) {
  const float* feat = (const float*)d_in[0];
  const float* W = (const float*)d_in[1];
  const float* bias = (const float*)d_in[2];
  float* out = (float*)d_out;
  float* absS = (float*)d_ws;                                   // B*N floats
  unsigned* cnt = (unsigned*)((char*)d_ws + (size_t)B_ * N_ * sizeof(float));

  hipMemsetAsync(cnt, 0, B_ * sizeof(unsigned), stream);        // graph-safe node
  fused_kernel<<<NBLK, 256, 0, stream>>>(feat, W, bias, absS, cnt, out);
}

// Round 4
// 111.716 us; speedup vs baseline: 2.8854x; 2.8854x over previous
//
#include <hip/hip_runtime.h>

// Problem constants: B=32, N=4096, C=1152, K = int(N*0.1) = 409
#define B_ 32
#define N_ 4096
#define C_ 1152
#define K_ 409

#define NBLK 2048
#define ITERS 16                 // 2048 blocks * 4 waves * 16 iters = 131072 patches
#define SWEEP 8192               // patches per sweep step (NBLK*4)

typedef float f32x4 __attribute__((ext_vector_type(4)));

// Kernel 1: absS[p] = |dot(feature[p,:], W) + bias|.
// Chip-wide sweep: iteration `it` covers patches [it*8192, (it+1)*8192) across
// all blocks, so the whole chip streams one contiguous moving window.
__global__ __launch_bounds__(256) void score_abs_kernel(
    const float* __restrict__ feat, const float* __restrict__ W,
    const float* __restrict__ bias, float* __restrict__ absS) {
  __shared__ f32x4 Ws[C_ / 4];  // 288 float4 = 4.5 KB
  for (int i = threadIdx.x; i < C_ / 4; i += 256)
    Ws[i] = reinterpret_cast<const f32x4*>(W)[i];
  __syncthreads();

  const int wave = threadIdx.x >> 6;
  const int lane = threadIdx.x & 63;
  const float b0 = bias[0];

  // W fragments pinned in registers for all iterations.
  const f32x4 w0 = Ws[lane];
  const f32x4 w1 = Ws[lane + 64];
  const f32x4 w2 = Ws[lane + 128];
  const f32x4 w3 = Ws[lane + 192];
  const f32x4 w4 = (lane < 32) ? Ws[256 + lane] : (f32x4)0.f;

  const int base = blockIdx.x * 4 + wave;
  const f32x4* fbase = reinterpret_cast<const f32x4*>(feat);
#pragma unroll 4
  for (int it = 0; it < ITERS; ++it) {
    const int patch = base + it * SWEEP;
    const f32x4* f4 = fbase + (size_t)patch * (C_ / 4);
    // Nontemporal: one-shot 604 MB stream, don't displace L2/L3 contents.
    f32x4 vacc = __builtin_nontemporal_load(&f4[lane]) * w0;
    vacc += __builtin_nontemporal_load(&f4[lane + 64]) * w1;
    vacc += __builtin_nontemporal_load(&f4[lane + 128]) * w2;
    vacc += __builtin_nontemporal_load(&f4[lane + 192]) * w3;
    if (lane < 32) vacc += __builtin_nontemporal_load(&f4[256 + lane]) * w4;
    float acc = vacc[0] + vacc[1] + vacc[2] + vacc[3];
#pragma unroll
    for (int off = 32; off > 0; off >>= 1)
      acc += __shfl_down(acc, off, 64);
    if (lane == 0) absS[patch] = fabsf(acc + b0);  // cached: kernel 2 re-reads
  }
}

// Kernel 2: per batch row, exact mean of top-K absolute scores.
// Byte-wise radix select: 4 passes of 256-bin LDS histogram + wave-shfl
// suffix scan. Valid since all values >= 0 (uint order == float order).
__global__ __launch_bounds__(256) void topk_mean_kernel(
    const float* __restrict__ absS, float* __restrict__ out) {
  __shared__ float vals[N_];     // 16 KB
  __shared__ unsigned hist[256];
  __shared__ unsigned wsum[4];
  __shared__ unsigned sel[2];    // {selected byte, new k}
  __shared__ unsigned cred[4];
  __shared__ float sredf[4];

  const int t = threadIdx.x;
  const int wave = t >> 6;
  const int lane = t & 63;
  const int b = blockIdx.x;

  const float4* row4 = reinterpret_cast<const float4*>(absS + (size_t)b * N_);
  for (int i = t; i < N_ / 4; i += 256)
    reinterpret_cast<float4*>(vals)[i] = row4[i];
  __syncthreads();

  unsigned prefix = 0, k = K_;
#pragma unroll
  for (int p = 0; p < 4; ++p) {
    const int shift = 24 - 8 * p;
    const unsigned hmask = (p == 0) ? 0u : (0xFFFFFFFFu << (shift + 8));
    hist[t] = 0;
    __syncthreads();
    for (int i = t; i < N_; i += 256) {
      const unsigned e = __float_as_uint(vals[i]);
      if ((e & hmask) == (prefix & hmask))
        atomicAdd(&hist[(e >> shift) & 255u], 1u);
    }
    __syncthreads();
    const unsigned own = hist[t];
    unsigned x = own;  // inclusive suffix scan within wave (bins t..wave_end)
#pragma unroll
    for (int off = 1; off < 64; off <<= 1) {
      const unsigned v = __shfl_down(x, off, 64);
      if (lane + off < 64) x += v;
    }
    if (lane == 0) wsum[wave] = x;
    __syncthreads();
    unsigned cum_ge = x;
    for (int w = wave + 1; w < 4; ++w) cum_ge += wsum[w];
    const unsigned cnt_gt = cum_ge - own;
    if (cum_ge >= k && cnt_gt < k) {  // exactly one thread
      sel[0] = (unsigned)t;
      sel[1] = k - cnt_gt;
    }
    __syncthreads();
    prefix |= sel[0] << shift;
    k = sel[1];
    __syncthreads();
  }
  const float thr = __uint_as_float(prefix);

  // Sum strictly-greater elements; ties filled at thr (exact top_k semantics).
  float sum = 0.f;
  unsigned cgt = 0;
  for (int i = t; i < N_; i += 256) {
    const float v = vals[i];
    if (v > thr) { sum += v; cgt++; }
  }
#pragma unroll
  for (int off = 32; off > 0; off >>= 1) {
    sum += __shfl_down(sum, off, 64);
    cgt += __shfl_down(cgt, off, 64);
  }
  if (lane == 0) { cred[wave] = cgt; sredf[wave] = sum; }
  __syncthreads();
  if (t == 0) {
    const unsigned cg = cred[0] + cred[1] + cred[2] + cred[3];
    const float sg = sredf[0] + sredf[1] + sredf[2] + sredf[3];
    out[b] = (sg + (float)(K_ - (int)cg) * thr) / (float)K_;
  }
}

extern "C" void kernel_launch(void* const* d_in, const int* in_sizes, int n_in,
                              void* d_out, int out_size, void* d_ws, size_t ws_size,
                              hipStream_t stream) {
  const float* feat = (const float*)d_in[0];
  const float* W = (const float*)d_in[1];
  const float* bias = (const float*)d_in[2];
  float* out = (float*)d_out;
  float* absS = (float*)d_ws;  // B*N floats = 512 KB

  score_abs_kernel<<<NBLK, 256, 0, stream>>>(feat, W, bias, absS);
  topk_mean_kernel<<<B_, 256, 0, stream>>>(absS, out);
}

// Round 5
// 101.829 us; speedup vs baseline: 3.1655x; 1.0971x over previous
//
#include <hip/hip_runtime.h>

// Problem constants: B=32, N=4096, C=1152, K = int(N*0.1) = 409
#define B_ 32
#define N_ 4096
#define C_ 1152
#define K_ 409

#define NBLK 2048
#define PATCH_PER_BLK 64          // (B_*N_)/NBLK, contiguous per block (round-2 layout)
#define GROUPS 4
#define GITERS 4                  // GROUPS*GITERS = 16 patches per wave

typedef float f32x4 __attribute__((ext_vector_type(4)));

// Kernel 1: absS[p] = |dot(feature[p,:], W) + bias|.
// Block-contiguous chunks (best measured layout); reductions deferred per
// 4-iteration group so 20 loads stream back-to-back between reduce phases.
__global__ __launch_bounds__(256) void score_abs_kernel(
    const float* __restrict__ feat, const float* __restrict__ W,
    const float* __restrict__ bias, float* __restrict__ absS) {
  __shared__ f32x4 Ws[C_ / 4];  // 288 float4 = 4.5 KB
  for (int i = threadIdx.x; i < C_ / 4; i += 256)
    Ws[i] = reinterpret_cast<const f32x4*>(W)[i];
  __syncthreads();

  const int wave = threadIdx.x >> 6;
  const int lane = threadIdx.x & 63;
  const float b0 = bias[0];

  const f32x4 w0 = Ws[lane];
  const f32x4 w1 = Ws[lane + 64];
  const f32x4 w2 = Ws[lane + 128];
  const f32x4 w3 = Ws[lane + 192];
  const f32x4 w4 = (lane < 32) ? Ws[256 + lane] : (f32x4)0.f;

  const int patch_base = blockIdx.x * PATCH_PER_BLK + wave;
  const f32x4* fbase = reinterpret_cast<const f32x4*>(feat);
#pragma unroll
  for (int g = 0; g < GROUPS; ++g) {
    float pacc[GITERS];
#pragma unroll
    for (int u = 0; u < GITERS; ++u) {
      const int patch = patch_base + (g * GITERS + u) * 4;
      const f32x4* f4 = fbase + (size_t)patch * (C_ / 4);
      f32x4 vacc = __builtin_nontemporal_load(&f4[lane]) * w0;
      vacc += __builtin_nontemporal_load(&f4[lane + 64]) * w1;
      vacc += __builtin_nontemporal_load(&f4[lane + 128]) * w2;
      vacc += __builtin_nontemporal_load(&f4[lane + 192]) * w3;
      if (lane < 32) vacc += __builtin_nontemporal_load(&f4[256 + lane]) * w4;
      pacc[u] = vacc[0] + vacc[1] + vacc[2] + vacc[3];
    }
#pragma unroll
    for (int u = 0; u < GITERS; ++u) {
      float a = pacc[u];
#pragma unroll
      for (int off = 32; off > 0; off >>= 1) a += __shfl_down(a, off, 64);
      if (lane == 0)
        absS[patch_base + (g * GITERS + u) * 4] = fabsf(a + b0);
    }
  }
}

// Kernel 2: per batch row, exact mean of top-K absolute scores.
// Row held in REGISTERS (16 floats/thread, static indices); 4 byte-wise
// radix-select passes over a 256-bin LDS histogram + wave-shfl suffix scan.
// Valid since all values >= 0 (uint order == float order).
__global__ __launch_bounds__(256) void topk_mean_kernel(
    const float* __restrict__ absS, float* __restrict__ out) {
  __shared__ unsigned hist[256];
  __shared__ unsigned wsum[4];
  __shared__ unsigned sel[2];    // {selected byte, new k}
  __shared__ unsigned cred[4];
  __shared__ float sredf[4];

  const int t = threadIdx.x;
  const int wave = t >> 6;
  const int lane = t & 63;
  const float4* row4 = reinterpret_cast<const float4*>(absS + (size_t)blockIdx.x * N_);

  const float4 r0 = row4[t];
  const float4 r1 = row4[t + 256];
  const float4 r2 = row4[t + 512];
  const float4 r3 = row4[t + 768];
  float v[16] = {r0.x, r0.y, r0.z, r0.w, r1.x, r1.y, r1.z, r1.w,
                 r2.x, r2.y, r2.z, r2.w, r3.x, r3.y, r3.z, r3.w};

  unsigned prefix = 0, k = K_;
#pragma unroll
  for (int p = 0; p < 4; ++p) {
    const int shift = 24 - 8 * p;
    const unsigned hmask = (p == 0) ? 0u : (0xFFFFFFFFu << (shift + 8));
    hist[t] = 0;
    __syncthreads();
#pragma unroll
    for (int i = 0; i < 16; ++i) {
      const unsigned e = __float_as_uint(v[i]);
      if ((e & hmask) == (prefix & hmask))
        atomicAdd(&hist[(e >> shift) & 255u], 1u);
    }
    __syncthreads();
    const unsigned own = hist[t];
    unsigned x = own;  // inclusive suffix scan within wave
#pragma unroll
    for (int off = 1; off < 64; off <<= 1) {
      const unsigned s = __shfl_down(x, off, 64);
      if (lane + off < 64) x += s;
    }
    if (lane == 0) wsum[wave] = x;
    __syncthreads();
    unsigned cum_ge = x;
    for (int w = wave + 1; w < 4; ++w) cum_ge += wsum[w];
    const unsigned cnt_gt = cum_ge - own;
    if (cum_ge >= k && cnt_gt < k) {  // exactly one thread
      sel[0] = (unsigned)t;
      sel[1] = k - cnt_gt;
    }
    __syncthreads();
    prefix |= sel[0] << shift;
    k = sel[1];
    __syncthreads();
  }
  const float thr = __uint_as_float(prefix);

  // Sum strictly-greater elements; ties filled at thr (exact top_k semantics).
  float sum = 0.f;
  unsigned cgt = 0;
#pragma unroll
  for (int i = 0; i < 16; ++i) {
    if (v[i] > thr) { sum += v[i]; cgt++; }
  }
#pragma unroll
  for (int off = 32; off > 0; off >>= 1) {
    sum += __shfl_down(sum, off, 64);
    cgt += __shfl_down(cgt, off, 64);
  }
  if (lane == 0) { cred[wave] = cgt; sredf[wave] = sum; }
  __syncthreads();
  if (t == 0) {
    const unsigned cg = cred[0] + cred[1] + cred[2] + cred[3];
    const float sg = sredf[0] + sredf[1] + sredf[2] + sredf[3];
    out[blockIdx.x] = (sg + (float)(K_ - (int)cg) * thr) / (float)K_;
  }
}

extern "C" void kernel_launch(void* const* d_in, const int* in_sizes, int n_in,
                              void* d_out, int out_size, void* d_ws, size_t ws_size,
                              hipStream_t stream) {
  const float* feat = (const float*)d_in[0];
  const float* W = (const float*)d_in[1];
  const float* bias = (const float*)d_in[2];
  float* out = (float*)d_out;
  float* absS = (float*)d_ws;  // B*N floats = 512 KB

  score_abs_kernel<<<NBLK, 256, 0, stream>>>(feat, W, bias, absS);
  topk_mean_kernel<<<B_, 256, 0, stream>>>(absS, out);
}